// Round 1
// baseline (395.747 us; speedup 1.0000x reference)
//
#include <hip/hip_runtime.h>

// SPDnet autoencoder, collapsed analytically:
//   out_b = D (E x_b E^T - EPS*I16) D^T + EPS*I128
// where E = Wenc2*Wenc1*Wenc0 (16x128), D = Wdec2*Wdec1*Wdec0 (128x16).
// Valid because: encoder ReEigs are no-ops (lambda_min >= 0.01 by interlacing),
// LogEig->ExpEig->ReEig is the identity, and decoder ReEigs clamp exactly the
// rank-deficient null space: reeig(W X W^T) = W X W^T + EPS*(I - W W^T) when
// all eig(X) >= EPS and W has orthonormal columns.
//
// R1: latency/barrier-bound fix. Stage-1 reads x straight from global
// (coalesced, no LDS staging, no in-loop barriers: 18 -> 5 barriers/block),
// E stored transposed so stage-1 E reads are 2x ds_read_b128 broadcast per k
// (was 8x scalar), 512-thread blocks process 2 batch elements (grid = B/2 =
// 1024 = exactly 4 blocks/CU x 256 CU, 32 waves/CU), setup spread over 16 blocks.

#define SPD_EPS 1e-4f

// ---------------- setup: build E (16x128) and D (128x16) in workspace -------
// 16 blocks: each block redundantly computes the small e1/d1 products, then
// block bi writes E row bi and D rows [8*bi, 8*bi+8).
__global__ __launch_bounds__(256) void setup_ED(
    const float* __restrict__ wenc0,  // 64x128
    const float* __restrict__ wenc1,  // 32x64
    const float* __restrict__ wenc2,  // 16x32
    const float* __restrict__ wdec0,  // 32x16
    const float* __restrict__ wdec1,  // 64x32
    const float* __restrict__ wdec2,  // 128x64
    float* __restrict__ wsE,          // out: 16x128
    float* __restrict__ wsD)          // out: 128x16
{
    __shared__ float e1[16 * 64];   // Wenc2 @ Wenc1
    __shared__ float d1[64 * 16];   // Wdec1 @ Wdec0
    const int t = threadIdx.x;
    const int bi = blockIdx.x;      // 0..15

    // e1 = Wenc2(16x32) @ Wenc1(32x64)
    for (int r = 0; r < 4; ++r) {
        int o = t + 256 * r;
        int i = o >> 6, j = o & 63;
        float acc = 0.f;
        for (int k = 0; k < 32; ++k) acc += wenc2[i * 32 + k] * wenc1[k * 64 + j];
        e1[o] = acc;
    }
    // d1 = Wdec1(64x32) @ Wdec0(32x16)
    for (int r = 0; r < 4; ++r) {
        int o = t + 256 * r;
        int p = o >> 4, m = o & 15;
        float acc = 0.f;
        for (int k = 0; k < 32; ++k) acc += wdec1[p * 32 + k] * wdec0[k * 16 + m];
        d1[o] = acc;
    }
    __syncthreads();

    if (t < 128) {
        // E row bi: E[bi][t] = e1 row bi @ Wenc0 col t
        float acc = 0.f;
        for (int k = 0; k < 64; ++k) acc += e1[bi * 64 + k] * wenc0[k * 128 + t];
        wsE[bi * 128 + t] = acc;
    } else {
        // D rows [8*bi, 8*bi+8)
        int u0 = t - 128;
        int p = bi * 8 + (u0 >> 4), m = u0 & 15;
        float acc = 0.f;
        for (int k = 0; k < 64; ++k) acc += wdec2[p * 64 + k] * d1[k * 16 + m];
        wsD[p * 16 + m] = acc;
    }
}

// ---------------- main: one block = 2 batch elements -------------------------
// 512 threads: sub = t>>8 picks the batch element, tl = t&255 is the
// per-element thread id (identical role to the old 256-thread layout).
//
// LDS layout (floats), total 9024 floats = 36096 B -> 4 blocks/CU, 32 waves/CU:
//   Et  : [0, 2048)              E^T: Et[k*16+i] = E[i][k]  (no pad; all reads
//                                are wave-broadcast or 16-consecutive-bank)
//   Dt  : [2048, 4160)           D^T: 16 rows x 128 cols, stride 132
//   per sub (base 4160 + sub*2432):
//     s   : 256                  16x16
//     buf : 2176                 union { t1 16x132 = 2112 | u 128x17 = 2176 }
__global__ __launch_bounds__(512, 8) void spdnet_main(
    const float* __restrict__ x,    // B x 128 x 128
    const float* __restrict__ wsE,  // 16x128
    const float* __restrict__ wsD,  // 128x16
    float* __restrict__ out)        // B x 128 x 128
{
    __shared__ __align__(16) float smem[4160 + 2 * 2432];
    float* Et = smem;
    float* Dt = smem + 2048;        // stride 132

    const int t = threadIdx.x;
    const int sub = t >> 8;
    const int tl = t & 255;
    float* s   = smem + 4160 + sub * 2432;
    float* buf = s + 256;           // t1 (stride 132) then reused as u (stride 17)

    const int b = blockIdx.x * 2 + sub;
    const float* xb = x + (size_t)b * 16384;
    float* ob = out + (size_t)b * 16384;

    // ---- load Et (transposed) and Dt (transposed, padded) -------------------
    // Et write: lanes have i fast-varying -> consecutive words, conflict-free.
    // Dt write: bank = (4m+p)%32, exactly 2-way (free).
    for (int r = 0; r < 4; ++r) {
        int o = t + 512 * r;            // 0..2047
        int i = o & 15, jj = o >> 4;
        Et[jj * 16 + i] = wsE[i * 128 + jj];
        Dt[i * 132 + jj] = wsD[jj * 16 + i];   // m = i, p = jj
    }
    __syncthreads();

    // ---- stage 1: t1 = E @ x_b (16x128), x read direct from global ----------
    // thread: column j = tl&127 (wave reads 256B contiguous per k), half
    // h = tl>>7 owns output rows [8h, 8h+8). E octet = 2 float4 LDS broadcasts.
    {
        const int j = tl & 127;
        const int h = tl >> 7;
        const float* ecol = Et + 8 * h;
        float acc[8];
#pragma unroll
        for (int ii = 0; ii < 8; ++ii) acc[ii] = 0.f;

#pragma unroll 4
        for (int k = 0; k < 128; ++k) {
            float xv = xb[k * 128 + j];
            float4 e0 = *(const float4*)(ecol + k * 16);
            float4 e1v = *(const float4*)(ecol + k * 16 + 4);
            acc[0] += e0.x * xv;  acc[1] += e0.y * xv;
            acc[2] += e0.z * xv;  acc[3] += e0.w * xv;
            acc[4] += e1v.x * xv; acc[5] += e1v.y * xv;
            acc[6] += e1v.z * xv; acc[7] += e1v.w * xv;
        }
        float* t1 = buf;
#pragma unroll
        for (int ii = 0; ii < 8; ++ii) t1[(8 * h + ii) * 132 + j] = acc[ii];
    }
    __syncthreads();

    // ---- stage 2: s = t1 @ E^T - EPS*I (16x16) ------------------------------
    {
        const int i = tl >> 4, m = tl & 15;
        const float* t1r = buf + i * 132;
        float accs = 0.f;
#pragma unroll 4
        for (int jj = 0; jj < 128; ++jj)
            accs += t1r[jj] * Et[jj * 16 + m];
        if (i == m) accs -= SPD_EPS;
        s[i * 16 + m] = accs;
    }
    __syncthreads();

    // ---- stage 3: u = D @ s (128x16), u overwrites t1 (dead after stage 2) --
    {
        const int p = tl & 127;
        const int hh = tl >> 7;         // owns cols [8hh, 8hh+8)
        const float* sr = s + 8 * hh;
        float accu[8];
#pragma unroll
        for (int r = 0; r < 8; ++r) accu[r] = 0.f;
#pragma unroll
        for (int i = 0; i < 16; ++i) {
            float dv = Dt[i * 132 + p];
            float4 s0 = *(const float4*)(sr + i * 16);
            float4 s1 = *(const float4*)(sr + i * 16 + 4);
            accu[0] += dv * s0.x; accu[1] += dv * s0.y;
            accu[2] += dv * s0.z; accu[3] += dv * s0.w;
            accu[4] += dv * s1.x; accu[5] += dv * s1.y;
            accu[6] += dv * s1.z; accu[7] += dv * s1.w;
        }
        float* u = buf;                 // stride 17: bank = (17p+c)%32, all distinct
#pragma unroll
        for (int r = 0; r < 8; ++r) u[p * 17 + 8 * hh + r] = accu[r];
    }
    __syncthreads();

    // ---- stage 4: out = u @ D^T + EPS*I, float4 stores ----------------------
    {
        const int q4 = (tl & 31) * 4;   // column quad
        const int pw = tl >> 5;         // 0..7
        const float* u = buf;
        for (int it = 0; it < 16; ++it) {
            int p = it * 8 + pw;
            float4 a4 = make_float4(0.f, 0.f, 0.f, 0.f);
#pragma unroll
            for (int m = 0; m < 16; ++m) {
                float uv = u[p * 17 + m];
                float4 d4 = *(const float4*)&Dt[m * 132 + q4];
                a4.x += uv * d4.x;
                a4.y += uv * d4.y;
                a4.z += uv * d4.z;
                a4.w += uv * d4.w;
            }
            int d = p - q4;
            if (d >= 0 && d < 4) (&a4.x)[d] += SPD_EPS;
            *(float4*)(ob + p * 128 + q4) = a4;
        }
    }
}

extern "C" void kernel_launch(void* const* d_in, const int* in_sizes, int n_in,
                              void* d_out, int out_size, void* d_ws, size_t ws_size,
                              hipStream_t stream) {
    const float* x     = (const float*)d_in[0];
    const float* wenc0 = (const float*)d_in[1];
    const float* wenc1 = (const float*)d_in[2];
    const float* wenc2 = (const float*)d_in[3];
    const float* wdec0 = (const float*)d_in[4];
    const float* wdec1 = (const float*)d_in[5];
    const float* wdec2 = (const float*)d_in[6];
    float* out = (float*)d_out;

    float* wsE = (float*)d_ws;          // 2048 floats
    float* wsD = wsE + 2048;            // 2048 floats

    const int B = in_sizes[0] / 16384;  // 2048 (even)

    setup_ED<<<16, 256, 0, stream>>>(wenc0, wenc1, wenc2, wdec0, wdec1, wdec2,
                                     wsE, wsD);
    spdnet_main<<<B / 2, 512, 0, stream>>>(x, wsE, wsD, out);
}

// Round 2
// 370.188 us; speedup vs baseline: 1.0690x; 1.0690x over previous
//
#include <hip/hip_runtime.h>

// SPDnet autoencoder, collapsed analytically:
//   out_b = D (E x_b E^T - EPS*I16) D^T + EPS*I128
// where E = Wenc2*Wenc1*Wenc0 (16x128), D = Wdec2*Wdec1*Wdec0 (128x16).
// Valid because: encoder ReEigs are no-ops (lambda_min >= 0.01 by interlacing),
// LogEig->ExpEig->ReEig is the identity, and decoder ReEigs clamp exactly the
// rank-deficient null space: reeig(W X W^T) = W X W^T + EPS*(I - W W^T) when
// all eig(X) >= EPS and W has orthonormal columns.
//
// R2: traffic fix. R1 read x twice (row-half split) -> 750 MB HBM/dispatch,
// L3 thrash, 3.37 TB/s wall. Now stage 1 splits the K-range across the two
// row-halves (each thread keeps all 16 output rows, 16 accs), so every x
// element is read from global EXACTLY once, coalesced; halves merge via one
// LDS partial-sum (1 extra barrier, 6 total). Output uses non-temporal
// stores so the write stream doesn't evict x from L3 (restores the
// inter-dispatch x retention R0 had). 512 threads / 2 elements per block,
// 36 KB LDS -> 4 blocks/CU, grid 1024 = exactly resident.

#define SPD_EPS 1e-4f

typedef float f32x4 __attribute__((ext_vector_type(4)));

// ---------------- setup: build E (16x128) and D (128x16) in workspace -------
// 16 blocks: each block redundantly computes the small e1/d1 products, then
// block bi writes E row bi and D rows [8*bi, 8*bi+8).
__global__ __launch_bounds__(256) void setup_ED(
    const float* __restrict__ wenc0,  // 64x128
    const float* __restrict__ wenc1,  // 32x64
    const float* __restrict__ wenc2,  // 16x32
    const float* __restrict__ wdec0,  // 32x16
    const float* __restrict__ wdec1,  // 64x32
    const float* __restrict__ wdec2,  // 128x64
    float* __restrict__ wsE,          // out: 16x128
    float* __restrict__ wsD)          // out: 128x16
{
    __shared__ float e1[16 * 64];   // Wenc2 @ Wenc1
    __shared__ float d1[64 * 16];   // Wdec1 @ Wdec0
    const int t = threadIdx.x;
    const int bi = blockIdx.x;      // 0..15

    // e1 = Wenc2(16x32) @ Wenc1(32x64)
    for (int r = 0; r < 4; ++r) {
        int o = t + 256 * r;
        int i = o >> 6, j = o & 63;
        float acc = 0.f;
        for (int k = 0; k < 32; ++k) acc += wenc2[i * 32 + k] * wenc1[k * 64 + j];
        e1[o] = acc;
    }
    // d1 = Wdec1(64x32) @ Wdec0(32x16)
    for (int r = 0; r < 4; ++r) {
        int o = t + 256 * r;
        int p = o >> 4, m = o & 15;
        float acc = 0.f;
        for (int k = 0; k < 32; ++k) acc += wdec1[p * 32 + k] * wdec0[k * 16 + m];
        d1[o] = acc;
    }
    __syncthreads();

    if (t < 128) {
        // E row bi: E[bi][t] = e1 row bi @ Wenc0 col t
        float acc = 0.f;
        for (int k = 0; k < 64; ++k) acc += e1[bi * 64 + k] * wenc0[k * 128 + t];
        wsE[bi * 128 + t] = acc;
    } else {
        // D rows [8*bi, 8*bi+8)
        int u0 = t - 128;
        int p = bi * 8 + (u0 >> 4), m = u0 & 15;
        float acc = 0.f;
        for (int k = 0; k < 64; ++k) acc += wdec2[p * 64 + k] * d1[k * 16 + m];
        wsD[p * 16 + m] = acc;
    }
}

// ---------------- main: one block = 2 batch elements -------------------------
// 512 threads: sub = t>>8 picks the batch element, tl = t&255 per-element tid.
//
// LDS layout (floats), total 9024 floats = 36096 B -> 4 blocks/CU, 32 waves/CU:
//   Et  : [0, 2048)              E^T: Et[k*16+i] = E[i][k]  (reads are wave-
//                                broadcast or 16-consecutive-bank: conflict-free)
//   Dt  : [2048, 4160)           D^T: 16 rows x 128 cols, stride 132
//   per sub (base 4160 + sub*2432):
//     s   : 256                  16x16
//     buf : 2176                 union { t1 16x132 = 2112 | u 128x17 = 2176 }
__global__ __launch_bounds__(512, 8) void spdnet_main(
    const float* __restrict__ x,    // B x 128 x 128
    const float* __restrict__ wsE,  // 16x128
    const float* __restrict__ wsD,  // 128x16
    float* __restrict__ out)        // B x 128 x 128
{
    __shared__ __align__(16) float smem[4160 + 2 * 2432];
    float* Et = smem;
    float* Dt = smem + 2048;        // stride 132

    const int t = threadIdx.x;
    const int sub = t >> 8;
    const int tl = t & 255;
    float* s   = smem + 4160 + sub * 2432;
    float* buf = s + 256;           // t1 (stride 132) then reused as u (stride 17)

    const int b = blockIdx.x * 2 + sub;
    const float* xb = x + (size_t)b * 16384;
    float* ob = out + (size_t)b * 16384;

    // ---- load Et (transposed) and Dt (transposed, padded) -------------------
    for (int r = 0; r < 4; ++r) {
        int o = t + 512 * r;            // 0..2047
        int i = o & 15, jj = o >> 4;
        Et[jj * 16 + i] = wsE[i * 128 + jj];
        Dt[i * 132 + jj] = wsD[jj * 16 + i];   // m = i, p = jj
    }
    __syncthreads();

    // ---- stage 1: t1 = E @ x_b (16x128), K-split, x read ONCE ---------------
    // thread: column j = tl&127; half h = tl>>7 accumulates k in [64h, 64h+64)
    // into all 16 output rows. Wave reads 256B contiguous x per k; every x
    // element touched by exactly one thread. E row = 4 float4 LDS broadcasts.
    {
        const int j = tl & 127;
        const int h = tl >> 7;
        const int k0 = h << 6;
        const float* xcol = xb + (size_t)k0 * 128 + j;
        const float* erow = Et + k0 * 16;
        float acc[16];
#pragma unroll
        for (int ii = 0; ii < 16; ++ii) acc[ii] = 0.f;

#pragma unroll 4
        for (int k = 0; k < 64; ++k) {
            float xv = xcol[k * 128];
            const float* er = erow + k * 16;
            f32x4 e0 = *(const f32x4*)(er);
            f32x4 e1v = *(const f32x4*)(er + 4);
            f32x4 e2 = *(const f32x4*)(er + 8);
            f32x4 e3 = *(const f32x4*)(er + 12);
            acc[0]  += e0.x  * xv; acc[1]  += e0.y  * xv;
            acc[2]  += e0.z  * xv; acc[3]  += e0.w  * xv;
            acc[4]  += e1v.x * xv; acc[5]  += e1v.y * xv;
            acc[6]  += e1v.z * xv; acc[7]  += e1v.w * xv;
            acc[8]  += e2.x  * xv; acc[9]  += e2.y  * xv;
            acc[10] += e2.z  * xv; acc[11] += e2.w  * xv;
            acc[12] += e3.x  * xv; acc[13] += e3.y  * xv;
            acc[14] += e3.z  * xv; acc[15] += e3.w  * xv;
        }
        float* t1 = buf;
        if (h == 0) {
#pragma unroll
            for (int ii = 0; ii < 16; ++ii) t1[ii * 132 + j] = acc[ii];
        }
        __syncthreads();
        if (h == 1) {
#pragma unroll
            for (int ii = 0; ii < 16; ++ii) t1[ii * 132 + j] += acc[ii];
        }
    }
    __syncthreads();

    // ---- stage 2: s = t1 @ E^T - EPS*I (16x16) ------------------------------
    {
        const int i = tl >> 4, m = tl & 15;
        const float* t1r = buf + i * 132;     // 16B-aligned (132*4 % 16 == 0... row base offset i*132 floats; i*132*4 B: 132*4=528 B, not 16B-mult for odd i — use scalar-safe f4 only when aligned)
        float accs = 0.f;
        // rows at odd i are 528B-offset (not 16B aligned) -> read t1 as 2x
        // float2-equivalent scalars; keep it simple & conflict-free: scalar t1,
        // scalar Et (both broadcast/consecutive-bank, conflict-free).
#pragma unroll 8
        for (int jj = 0; jj < 128; ++jj)
            accs += t1r[jj] * Et[jj * 16 + m];
        if (i == m) accs -= SPD_EPS;
        s[i * 16 + m] = accs;
    }
    __syncthreads();

    // ---- stage 3: u = D @ s (128x16), u overwrites t1 (dead after stage 2) --
    {
        const int p = tl & 127;
        const int hh = tl >> 7;         // owns cols [8hh, 8hh+8)
        const float* sr = s + 8 * hh;
        float accu[8];
#pragma unroll
        for (int r = 0; r < 8; ++r) accu[r] = 0.f;
#pragma unroll
        for (int i = 0; i < 16; ++i) {
            float dv = Dt[i * 132 + p];
            f32x4 s0 = *(const f32x4*)(sr + i * 16);
            f32x4 s1 = *(const f32x4*)(sr + i * 16 + 4);
            accu[0] += dv * s0.x; accu[1] += dv * s0.y;
            accu[2] += dv * s0.z; accu[3] += dv * s0.w;
            accu[4] += dv * s1.x; accu[5] += dv * s1.y;
            accu[6] += dv * s1.z; accu[7] += dv * s1.w;
        }
        float* u = buf;                 // stride 17: bank = (17p+c)%32, 2-way max
#pragma unroll
        for (int r = 0; r < 8; ++r) u[p * 17 + 8 * hh + r] = accu[r];
    }
    __syncthreads();

    // ---- stage 4: out = u @ D^T + EPS*I, non-temporal float4 stores ---------
    // nt stores keep the 134 MB write stream out of L3 so x stays resident
    // across dispatches.
    {
        const int q4 = (tl & 31) * 4;   // column quad
        const int pw = tl >> 5;         // 0..7
        const float* u = buf;
        for (int it = 0; it < 16; ++it) {
            int p = it * 8 + pw;
            f32x4 a4 = {0.f, 0.f, 0.f, 0.f};
#pragma unroll
            for (int m = 0; m < 16; ++m) {
                float uv = u[p * 17 + m];
                f32x4 d4 = *(const f32x4*)&Dt[m * 132 + q4];
                a4.x += uv * d4.x;
                a4.y += uv * d4.y;
                a4.z += uv * d4.z;
                a4.w += uv * d4.w;
            }
            int d = p - q4;
            if (d >= 0 && d < 4) a4[d] += SPD_EPS;
            __builtin_nontemporal_store(a4, (f32x4*)(ob + p * 128 + q4));
        }
    }
}

extern "C" void kernel_launch(void* const* d_in, const int* in_sizes, int n_in,
                              void* d_out, int out_size, void* d_ws, size_t ws_size,
                              hipStream_t stream) {
    const float* x     = (const float*)d_in[0];
    const float* wenc0 = (const float*)d_in[1];
    const float* wenc1 = (const float*)d_in[2];
    const float* wenc2 = (const float*)d_in[3];
    const float* wdec0 = (const float*)d_in[4];
    const float* wdec1 = (const float*)d_in[5];
    const float* wdec2 = (const float*)d_in[6];
    float* out = (float*)d_out;

    float* wsE = (float*)d_ws;          // 2048 floats
    float* wsD = wsE + 2048;            // 2048 floats

    const int B = in_sizes[0] / 16384;  // 2048 (even)

    setup_ED<<<16, 256, 0, stream>>>(wenc0, wenc1, wenc2, wdec0, wdec1, wdec2,
                                     wsE, wsD);
    spdnet_main<<<B / 2, 512, 0, stream>>>(x, wsE, wsD, out);
}